// Round 1
// baseline (401.866 us; speedup 1.0000x reference)
//
#include <hip/hip_runtime.h>

// Problem constants
#define M_TOT 12544   // 64 images * 196 patches
#define K_PE  768     // 3*16*16
#define HID   384
#define K_CE  75264   // 196*384 per image

// ---------------- zero the CE accumulator (ws is poisoned 0xAA) -------------
__global__ __launch_bounds__(256) void zero_ce(float* __restrict__ ce) {
    int i = blockIdx.x * 256 + threadIdx.x;
    if (i < 4096) ce[i] = 0.f;
}

// ---------------- patch-embed GEMM (im2col on the fly), fp32 ----------------
// grid (196, 6, 2): 64-wide M tiles, 64-wide N tiles, z = x|y. block 256.
__global__ __launch_bounds__(256) void patch_embed(
    const float* __restrict__ xin, const float* __restrict__ yin,
    const float* __restrict__ Wt,  const float* __restrict__ bias,
    float* __restrict__ xe, float* __restrict__ ye) {
    const float* im  = blockIdx.z ? yin : xin;
    float*       out = blockIdx.z ? ye  : xe;
    const int mtile = blockIdx.x * 64;
    const int ntile = blockIdx.y * 64;
    __shared__ float As[16][68];   // [k][m], pad 68 -> 2-way max (free)
    __shared__ float Bs[16][68];   // [k][n]
    const int tid = threadIdx.x;
    const int tx = tid & 15;       // n quad
    const int ty = tid >> 4;       // m quad
    const int lk = tid & 15;       // loader: k within chunk (== dj)
    const int lr = tid >> 4;       // loader: row base

    // Precompute global row bases for the 4 A rows this thread stages.
    int abase[4];
#pragma unroll
    for (int p = 0; p < 4; ++p) {
        int mg = mtile + lr + p * 16;
        int b  = mg / 196;
        int r  = mg - b * 196;
        int i  = r / 14;
        int j  = r - i * 14;
        // x[((b*3 + c)*224 + i*16+di)*224 + j*16+dj]
        abase[p] = ((b * 3) * 224 + i * 16) * 224 + j * 16;
    }

    float acc[4][4] = {};
    for (int kb = 0; kb < 768; kb += 16) {
        const int c  = kb >> 8;
        const int di = (kb >> 4) & 15;
        const int aoff = (c * 224 + di) * 224 + lk;
#pragma unroll
        for (int p = 0; p < 4; ++p)
            As[lk][lr + p * 16] = im[abase[p] + aoff];
#pragma unroll
        for (int p = 0; p < 4; ++p)
            Bs[lk][lr + p * 16] = Wt[(ntile + lr + p * 16) * 768 + kb + lk];
        __syncthreads();
#pragma unroll
        for (int kk = 0; kk < 16; ++kk) {
            float4 a4 = *(const float4*)&As[kk][ty * 4];
            float4 b4 = *(const float4*)&Bs[kk][tx * 4];
            float av[4] = {a4.x, a4.y, a4.z, a4.w};
            float bv[4] = {b4.x, b4.y, b4.z, b4.w};
#pragma unroll
            for (int mi = 0; mi < 4; ++mi)
#pragma unroll
                for (int ni = 0; ni < 4; ++ni)
                    acc[mi][ni] += av[mi] * bv[ni];
        }
        __syncthreads();
    }
    const float4 bb = *(const float4*)&bias[ntile + tx * 4];
#pragma unroll
    for (int mi = 0; mi < 4; ++mi) {
        int mg = mtile + ty * 4 + mi;
        float4 o;
        o.x = acc[mi][0] + bb.x;
        o.y = acc[mi][1] + bb.y;
        o.z = acc[mi][2] + bb.z;
        o.w = acc[mi][3] + bb.w;
        *(float4*)&out[(size_t)mg * HID + ntile + tx * 4] = o;
    }
}

// ---------------- row softmax / log-softmax, in place -----------------------
// grid (12544, 2): y==0 -> log_softmax(xe), y==1 -> softmax(ye). 1 wave/row.
__global__ __launch_bounds__(64) void softmax_inplace(float* __restrict__ xe,
                                                      float* __restrict__ ye) {
    float* row = (blockIdx.y ? ye : xe) + (size_t)blockIdx.x * HID;
    const int lane = threadIdx.x;
    float v[6];
    float m = -3.4e38f;
#pragma unroll
    for (int p = 0; p < 6; ++p) { v[p] = row[lane + p * 64]; m = fmaxf(m, v[p]); }
#pragma unroll
    for (int off = 32; off > 0; off >>= 1) m = fmaxf(m, __shfl_xor(m, off));
    float s = 0.f;
#pragma unroll
    for (int p = 0; p < 6; ++p) { v[p] -= m; s += __expf(v[p]); }
#pragma unroll
    for (int off = 32; off > 0; off >>= 1) s += __shfl_xor(s, off);
    if (blockIdx.y == 0) {
        float ls = __logf(s);
#pragma unroll
        for (int p = 0; p < 6; ++p) row[lane + p * 64] = v[p] - ls;
    } else {
        float inv = 1.f / s;
#pragma unroll
        for (int p = 0; p < 6; ++p) row[lane + p * 64] = __expf(v[p]) * inv;
    }
}

// ---------------- CE: 64x64 GEMM over K=75264, split-K + atomics ------------
// CE_raw[i][j] = sum_k logp[i*75264+k] * q[j*75264+k]   (sign/scale cancel in ratio)
// grid 588 (K chunks of 128), block 256, each thread 4x4 of the 64x64 output.
__global__ __launch_bounds__(256) void ce_partial(const float* __restrict__ logp,
                                                  const float* __restrict__ q,
                                                  float* __restrict__ ce) {
    __shared__ float Lt[64][68];   // [k][i]
    __shared__ float Qt[64][68];   // [k][j]
    const int tid = threadIdx.x;
    const int tx = tid & 15;       // j quad
    const int ty = tid >> 4;       // i quad
    float acc[4][4] = {};
    const int kbeg = blockIdx.x * 128;
    for (int k0 = kbeg; k0 < kbeg + 128; k0 += 64) {
#pragma unroll
        for (int l = 0; l < 16; ++l) {
            int idx = tid + l * 256;           // 0..4095
            int row = idx >> 6;
            int k   = idx & 63;
            Lt[k][row] = logp[(size_t)row * K_CE + k0 + k];
            Qt[k][row] = q[(size_t)row * K_CE + k0 + k];
        }
        __syncthreads();
#pragma unroll 8
        for (int kk = 0; kk < 64; ++kk) {
            float4 a4 = *(const float4*)&Lt[kk][ty * 4];
            float4 b4 = *(const float4*)&Qt[kk][tx * 4];
            float av[4] = {a4.x, a4.y, a4.z, a4.w};
            float bv[4] = {b4.x, b4.y, b4.z, b4.w};
#pragma unroll
            for (int mi = 0; mi < 4; ++mi)
#pragma unroll
                for (int ni = 0; ni < 4; ++ni)
                    acc[mi][ni] += av[mi] * bv[ni];
        }
        __syncthreads();
    }
#pragma unroll
    for (int mi = 0; mi < 4; ++mi)
#pragma unroll
        for (int ni = 0; ni < 4; ++ni)
            atomicAdd(&ce[(ty * 4 + mi) * 64 + tx * 4 + ni], acc[mi][ni]);
}

// ---------------- final scalar ----------------------------------------------
// close/far: the -1/196 factor in CE cancels in the ratio.
__global__ __launch_bounds__(256) void finalize(const float* __restrict__ ce,
                                                float* __restrict__ out) {
    __shared__ float s_tr[4], s_tot[4];
    float tr = 0.f, tot = 0.f;
    for (int idx = threadIdx.x; idx < 4096; idx += 256) {
        float v = ce[idx];
        tot += v;
        if ((idx >> 6) == (idx & 63)) tr += v;
    }
#pragma unroll
    for (int off = 32; off > 0; off >>= 1) {
        tr  += __shfl_xor(tr, off);
        tot += __shfl_xor(tot, off);
    }
    int wave = threadIdx.x >> 6;
    if ((threadIdx.x & 63) == 0) { s_tr[wave] = tr; s_tot[wave] = tot; }
    __syncthreads();
    if (threadIdx.x == 0) {
        float T = s_tr[0] + s_tr[1] + s_tr[2] + s_tr[3];
        float S = s_tot[0] + s_tot[1] + s_tot[2] + s_tot[3];
        float close = T / 64.f;
        float far   = (S - T) / (4096.f - 64.f);
        out[0] = close / far;
    }
}

extern "C" void kernel_launch(void* const* d_in, const int* in_sizes, int n_in,
                              void* d_out, int out_size, void* d_ws, size_t ws_size,
                              hipStream_t stream) {
    const float* x = (const float*)d_in[0];   // (64,3,224,224)
    const float* y = (const float*)d_in[1];   // (64,3,224,224)
    const float* W = (const float*)d_in[2];   // (384,3,16,16)
    const float* b = (const float*)d_in[3];   // (384,)
    float* out = (float*)d_out;               // scalar f32

    float* ce = (float*)d_ws;                 // 4096 floats
    float* xe = ce + 4096;                    // 12544*384
    float* ye = xe + (size_t)M_TOT * HID;     // 12544*384

    zero_ce<<<16, 256, 0, stream>>>(ce);
    patch_embed<<<dim3(196, 6, 2), 256, 0, stream>>>(x, y, W, b, xe, ye);
    softmax_inplace<<<dim3(M_TOT, 2), 64, 0, stream>>>(xe, ye);
    ce_partial<<<588, 256, 0, stream>>>(xe, ye, ce);
    finalize<<<1, 256, 0, stream>>>(ce, out);
}

// Round 2
// 188.331 us; speedup vs baseline: 2.1338x; 2.1338x over previous
//
#include <hip/hip_runtime.h>

// Problem constants
#define M_TOT 12544   // 64 images * 196 patches
#define HID   384
#define K_PE  768     // 3*16*16
#define K_CE  75264   // 196*384 per image

using f32x4  = __attribute__((ext_vector_type(4))) float;
using short8 = __attribute__((ext_vector_type(8))) short;

// ---- bf16 helpers (RNE) ----------------------------------------------------
__device__ __forceinline__ unsigned short f2bf(float x) {
    union { float f; unsigned u; } v; v.f = x;
    return (unsigned short)((v.u + 0x7fffu + ((v.u >> 16) & 1u)) >> 16);
}
__device__ __forceinline__ unsigned bfpack(float lo, float hi) {
    union { float f; unsigned u; } a, b; a.f = lo; b.f = hi;
    unsigned ra = (a.u + 0x7fffu + ((a.u >> 16) & 1u)) >> 16;
    unsigned rb = (b.u + 0x7fffu + ((b.u >> 16) & 1u)) & 0xffff0000u;
    return ra | rb;
}
__device__ __forceinline__ float bf2f(unsigned short u) {
    union { unsigned u; float f; } v; v.u = ((unsigned)u) << 16; return v.f;
}

// ---------------- zero the CE accumulator (ws is poisoned 0xAA) -------------
__global__ __launch_bounds__(256) void zero_ce(float* __restrict__ ce) {
    int i = blockIdx.x * 256 + threadIdx.x;
    if (i < 4096) ce[i] = 0.f;
}

// ---------------- patch-embed GEMM via bf16 MFMA ----------------------------
// M=12544 patches, N=384 hidden, K=768. grid (98, 3, 2): 128M x 128N tiles,
// z = x|y. block 256 = 4 waves, each wave computes 64x64 (4x4 frags 16x16x32).
__global__ __launch_bounds__(256) void patch_embed_mfma(
    const float* __restrict__ xin, const float* __restrict__ yin,
    const float* __restrict__ Wt,  const float* __restrict__ bias,
    unsigned short* __restrict__ xe, unsigned short* __restrict__ ye) {
    const float* im  = blockIdx.z ? yin : xin;
    unsigned short* out = blockIdx.z ? ye : xe;
    const int mtile = blockIdx.x * 128;
    const int ntile = blockIdx.y * 128;

    __shared__ unsigned short As[128][32];  // [m][k] row-major, bf16
    __shared__ unsigned short Bs[128][32];  // [n][k] row-major, bf16

    const int tid  = threadIdx.x;
    const int sm   = tid >> 1;   // staged row (0..127)
    const int half = tid & 1;    // which 16-wide k half

    // A row base: patch (image pb, patch row pi, patch col pj)
    int mg = mtile + sm;
    int pb = mg / 196;
    int pr = mg - pb * 196;
    int pi = pr / 14;
    int pj = pr - pi * 14;
    const float* aptr0 = im + (((size_t)pb * 3) * 224 + pi * 16) * 224 + pj * 16;
    const float* bptr0 = Wt + (size_t)(ntile + sm) * K_PE + half * 16;

    const int wave = tid >> 6;
    const int lane = tid & 63;
    const int wm = (wave & 1) * 64;
    const int wn = (wave >> 1) * 64;
    const int lm = lane & 15;    // row-in-16 (A) / col-in-16 (B)
    const int lq = lane >> 4;    // quad

    f32x4 acc[4][4] = {};

    for (int kb = 0; kb < K_PE; kb += 32) {
        // ---- stage A: 16 fp32 -> 16 bf16 per thread
        {
            const int c  = kb >> 8;
            const int di = ((kb >> 4) & 15) + half;
            const float* ap = aptr0 + (c * 224 + di) * 224;
            float4 f0 = *(const float4*)(ap);
            float4 f1 = *(const float4*)(ap + 4);
            float4 f2 = *(const float4*)(ap + 8);
            float4 f3 = *(const float4*)(ap + 12);
            uint4 p0, p1;
            p0.x = bfpack(f0.x, f0.y); p0.y = bfpack(f0.z, f0.w);
            p0.z = bfpack(f1.x, f1.y); p0.w = bfpack(f1.z, f1.w);
            p1.x = bfpack(f2.x, f2.y); p1.y = bfpack(f2.z, f2.w);
            p1.z = bfpack(f3.x, f3.y); p1.w = bfpack(f3.z, f3.w);
            ((uint4*)&As[sm][half * 16])[0] = p0;
            ((uint4*)&As[sm][half * 16])[1] = p1;
        }
        // ---- stage B
        {
            const float* bp = bptr0 + kb;
            float4 f0 = *(const float4*)(bp);
            float4 f1 = *(const float4*)(bp + 4);
            float4 f2 = *(const float4*)(bp + 8);
            float4 f3 = *(const float4*)(bp + 12);
            uint4 p0, p1;
            p0.x = bfpack(f0.x, f0.y); p0.y = bfpack(f0.z, f0.w);
            p0.z = bfpack(f1.x, f1.y); p0.w = bfpack(f1.z, f1.w);
            p1.x = bfpack(f2.x, f2.y); p1.y = bfpack(f2.z, f2.w);
            p1.z = bfpack(f3.x, f3.y); p1.w = bfpack(f3.z, f3.w);
            ((uint4*)&Bs[sm][half * 16])[0] = p0;
            ((uint4*)&Bs[sm][half * 16])[1] = p1;
        }
        __syncthreads();
        short8 af[4], bf_[4];
#pragma unroll
        for (int mi = 0; mi < 4; ++mi)
            af[mi] = *(const short8*)&As[wm + mi * 16 + lm][lq * 8];
#pragma unroll
        for (int ni = 0; ni < 4; ++ni)
            bf_[ni] = *(const short8*)&Bs[wn + ni * 16 + lm][lq * 8];
#pragma unroll
        for (int mi = 0; mi < 4; ++mi)
#pragma unroll
            for (int ni = 0; ni < 4; ++ni)
                acc[mi][ni] = __builtin_amdgcn_mfma_f32_16x16x32_bf16(
                    af[mi], bf_[ni], acc[mi][ni], 0, 0, 0);
        __syncthreads();
    }

    // Epilogue: D layout col=lane&15, row=(lane>>4)*4+reg. Add bias, store bf16.
#pragma unroll
    for (int ni = 0; ni < 4; ++ni) {
        const int col = ntile + wn + ni * 16 + lm;
        const float bv = bias[col];
#pragma unroll
        for (int mi = 0; mi < 4; ++mi) {
            const int row0 = mtile + wm + mi * 16 + lq * 4;
#pragma unroll
            for (int r = 0; r < 4; ++r)
                out[(size_t)(row0 + r) * HID + col] = f2bf(acc[mi][ni][r] + bv);
        }
    }
}

// ---------------- row softmax / log-softmax, bf16 in/out, in place ----------
// grid (3136, 2): 4 rows/block (1 wave per row). y==0 -> log_softmax(xe),
// y==1 -> softmax(ye).
__global__ __launch_bounds__(256) void softmax_bf16(unsigned short* __restrict__ xe,
                                                    unsigned short* __restrict__ ye) {
    const int rowi = blockIdx.x * 4 + (threadIdx.x >> 6);
    unsigned short* row = (blockIdx.y ? ye : xe) + (size_t)rowi * HID;
    const int lane = threadIdx.x & 63;
    float v[6];
    float m = -3.4e38f;
#pragma unroll
    for (int p = 0; p < 6; ++p) { v[p] = bf2f(row[p * 64 + lane]); m = fmaxf(m, v[p]); }
#pragma unroll
    for (int off = 32; off > 0; off >>= 1) m = fmaxf(m, __shfl_xor(m, off));
    float s = 0.f;
#pragma unroll
    for (int p = 0; p < 6; ++p) { v[p] -= m; s += __expf(v[p]); }
#pragma unroll
    for (int off = 32; off > 0; off >>= 1) s += __shfl_xor(s, off);
    if (blockIdx.y == 0) {
        float ls = __logf(s);
#pragma unroll
        for (int p = 0; p < 6; ++p) row[p * 64 + lane] = f2bf(v[p] - ls);
    } else {
        float inv = 1.f / s;
#pragma unroll
        for (int p = 0; p < 6; ++p) row[p * 64 + lane] = f2bf(__expf(v[p]) * inv);
    }
}

// ---------------- CE: 64x64 GEMM over K=75264, bf16 MFMA, split-K -----------
// S[i][j] = sum_k logp[i][k] * q[j][k]  (sign/scale cancel in close/far ratio)
// grid 392 (K chunks of 192), block 256 = 4 waves, each wave 32x32 (2x2 frags).
__global__ __launch_bounds__(256) void ce_mfma(const unsigned short* __restrict__ logp,
                                               const unsigned short* __restrict__ q,
                                               float* __restrict__ ce) {
    __shared__ unsigned short Lt[64][64];  // [i][k]
    __shared__ unsigned short Qt[64][64];  // [j][k]
    const int tid  = threadIdx.x;
    const int wave = tid >> 6;
    const int lane = tid & 63;
    const int ib = (wave & 1) * 32;
    const int jb = (wave >> 1) * 32;
    const int lm = lane & 15;
    const int lq = lane >> 4;
    f32x4 acc[2][2] = {};
    const int kbeg = blockIdx.x * 192;
    for (int k0 = kbeg; k0 < kbeg + 192; k0 += 64) {
#pragma unroll
        for (int s = 0; s < 2; ++s) {
            int seg = tid + s * 256;         // 0..511
            int r   = seg >> 3;              // row 0..63
            int kk  = (seg & 7) * 8;         // 0..56
            *(uint4*)&Lt[r][kk] = *(const uint4*)&logp[(size_t)r * K_CE + k0 + kk];
            *(uint4*)&Qt[r][kk] = *(const uint4*)&q[(size_t)r * K_CE + k0 + kk];
        }
        __syncthreads();
#pragma unroll
        for (int ks = 0; ks < 2; ++ks) {
            short8 af[2], bf_[2];
#pragma unroll
            for (int mi = 0; mi < 2; ++mi)
                af[mi] = *(const short8*)&Lt[ib + mi * 16 + lm][ks * 32 + lq * 8];
#pragma unroll
            for (int ni = 0; ni < 2; ++ni)
                bf_[ni] = *(const short8*)&Qt[jb + ni * 16 + lm][ks * 32 + lq * 8];
#pragma unroll
            for (int mi = 0; mi < 2; ++mi)
#pragma unroll
                for (int ni = 0; ni < 2; ++ni)
                    acc[mi][ni] = __builtin_amdgcn_mfma_f32_16x16x32_bf16(
                        af[mi], bf_[ni], acc[mi][ni], 0, 0, 0);
        }
        __syncthreads();
    }
#pragma unroll
    for (int mi = 0; mi < 2; ++mi)
#pragma unroll
        for (int ni = 0; ni < 2; ++ni)
#pragma unroll
            for (int r = 0; r < 4; ++r)
                atomicAdd(&ce[(ib + mi * 16 + lq * 4 + r) * 64 + jb + ni * 16 + lm],
                          acc[mi][ni][r]);
}

// ---------------- final scalar ----------------------------------------------
__global__ __launch_bounds__(256) void finalize(const float* __restrict__ ce,
                                                float* __restrict__ out) {
    __shared__ float s_tr[4], s_tot[4];
    float tr = 0.f, tot = 0.f;
    for (int idx = threadIdx.x; idx < 4096; idx += 256) {
        float v = ce[idx];
        tot += v;
        if ((idx >> 6) == (idx & 63)) tr += v;
    }
#pragma unroll
    for (int off = 32; off > 0; off >>= 1) {
        tr  += __shfl_xor(tr, off);
        tot += __shfl_xor(tot, off);
    }
    int wave = threadIdx.x >> 6;
    if ((threadIdx.x & 63) == 0) { s_tr[wave] = tr; s_tot[wave] = tot; }
    __syncthreads();
    if (threadIdx.x == 0) {
        float T = s_tr[0] + s_tr[1] + s_tr[2] + s_tr[3];
        float S = s_tot[0] + s_tot[1] + s_tot[2] + s_tot[3];
        float close = T / 64.f;
        float far   = (S - T) / (4096.f - 64.f);
        out[0] = close / far;
    }
}

extern "C" void kernel_launch(void* const* d_in, const int* in_sizes, int n_in,
                              void* d_out, int out_size, void* d_ws, size_t ws_size,
                              hipStream_t stream) {
    const float* x = (const float*)d_in[0];   // (64,3,224,224)
    const float* y = (const float*)d_in[1];   // (64,3,224,224)
    const float* W = (const float*)d_in[2];   // (384,3,16,16) == (384,768)
    const float* b = (const float*)d_in[3];   // (384,)
    float* out = (float*)d_out;               // scalar f32

    float* ce = (float*)d_ws;                                  // 4096 f32
    unsigned short* xe = (unsigned short*)(ce + 4096);         // 12544*384 bf16
    unsigned short* ye = xe + (size_t)M_TOT * HID;             // 12544*384 bf16

    zero_ce<<<16, 256, 0, stream>>>(ce);
    patch_embed_mfma<<<dim3(98, 3, 2), 256, 0, stream>>>(x, y, W, b, xe, ye);
    softmax_bf16<<<dim3(3136, 2), 256, 0, stream>>>(xe, ye);
    ce_mfma<<<392, 256, 0, stream>>>(xe, ye, ce);
    finalize<<<1, 256, 0, stream>>>(ce, out);
}

// Round 3
// 181.947 us; speedup vs baseline: 2.2087x; 1.0351x over previous
//
#include <hip/hip_runtime.h>

#define M_TOT 12544   // 64 images * 196 patches
#define HID   384
#define K_PE  768     // 3*16*16
#define K_CE  75264   // 196*384 per image

typedef unsigned short ushort_t;
using f32x4  = __attribute__((ext_vector_type(4))) float;
using short8 = __attribute__((ext_vector_type(8))) short;

// ---- bf16 helpers (RNE) ----------------------------------------------------
__device__ __forceinline__ unsigned short f2bf(float x) {
    union { float f; unsigned u; } v; v.f = x;
    return (unsigned short)((v.u + 0x7fffu + ((v.u >> 16) & 1u)) >> 16);
}
__device__ __forceinline__ unsigned bfpack(float lo, float hi) {
    union { float f; unsigned u; } a, b; a.f = lo; b.f = hi;
    unsigned ra = (a.u + 0x7fffu + ((a.u >> 16) & 1u)) >> 16;
    unsigned rb = (b.u + 0x7fffu + ((b.u >> 16) & 1u)) & 0xffff0000u;
    return ra | rb;
}
__device__ __forceinline__ float bflo(unsigned u) {
    union { unsigned u; float f; } v; v.u = u << 16; return v.f;
}
__device__ __forceinline__ float bfhi(unsigned u) {
    union { unsigned u; float f; } v; v.u = u & 0xffff0000u; return v.f;
}
__device__ __forceinline__ float bf2f(unsigned short u) {
    union { unsigned u; float f; } v; v.u = ((unsigned)u) << 16; return v.f;
}

// ---- async global->LDS, 16 B per lane (LDS dest = wave-uniform base) -------
__device__ __forceinline__ void gl_lds16(const void* g, void* l) {
    __builtin_amdgcn_global_load_lds(
        (const __attribute__((address_space(1))) unsigned*)g,
        (__attribute__((address_space(3))) unsigned*)l, 16, 0, 0);
}

// ---------------- prep: zero scalars + convert W to bf16 --------------------
// 36864 threads, 8 elems each (294912 total). grid 144 x 256.
__global__ __launch_bounds__(256) void prep(const float* __restrict__ W,
                                            ushort_t* __restrict__ Wbf,
                                            float* __restrict__ scal) {
    int idx = blockIdx.x * 256 + threadIdx.x;
    if (idx < 4) scal[idx] = 0.f;
    const float4 a = *(const float4*)(W + (size_t)idx * 8);
    const float4 b = *(const float4*)(W + (size_t)idx * 8 + 4);
    uint4 p;
    p.x = bfpack(a.x, a.y); p.y = bfpack(a.z, a.w);
    p.z = bfpack(b.x, b.y); p.w = bfpack(b.z, b.w);
    ((uint4*)Wbf)[idx] = p;
}

// ---------------- patch-embed GEMM via bf16 MFMA ----------------------------
// M=12544, N=384, K=768. Tile 64M x 128N, K-step 64. grid (196, 3, 2).
// Block 256 = 4 waves (2M x 2N), wave tile 32x64 (2x4 frags of 16x16x32).
// LDS layout: packed rows of 8 16-B chunks, chunk XOR-swizzled by (row&7).
// B staged via global_load_lds (bf16 W, zero staging VALU); A staged with
// fused fp32->bf16 cvt.
__global__ __launch_bounds__(256) void patch_embed_mfma(
    const float* __restrict__ xin, const float* __restrict__ yin,
    const ushort_t* __restrict__ Wbf, const float* __restrict__ bias,
    ushort_t* __restrict__ xe, ushort_t* __restrict__ ye) {
    const float* im   = blockIdx.z ? yin : xin;
    ushort_t*    outp = blockIdx.z ? ye  : xe;
    const int mtile = blockIdx.x * 64;
    const int ntile = blockIdx.y * 128;

    __shared__ __align__(16) ushort_t As[64 * 64];    // 8 KB
    __shared__ __align__(16) ushort_t Bs[128 * 64];   // 16 KB

    const int tid  = threadIdx.x;
    const int wave = tid >> 6;
    const int lane = tid & 63;
    const int lm   = lane & 15;
    const int lq   = lane >> 4;
    const int wm   = (wave & 1) * 32;
    const int wn   = (wave >> 1) * 64;

    // ---- A staging ids: thread -> (row sm, 16-elem k-seg qt)
    const int sm = tid >> 2;          // 0..63
    const int qt = tid & 3;           // 0..3
    {
        // nothing
    }
    int mg = mtile + sm;
    int pb = mg / 196;
    int pr = mg - pb * 196;
    int pi = pr / 14;
    int pj = pr - pi * 14;
    const float* aptr = im + ((size_t)(pb * 3) * 224 + pi * 16) * 224 + pj * 16;
    ushort_t* aw0 = &As[sm * 64 + (((qt * 2    ) ^ (sm & 7)) * 8)];
    ushort_t* aw1 = &As[sm * 64 + (((qt * 2 + 1) ^ (sm & 7)) * 8)];

    // ---- B staging: lane-fixed global column offset (XOR pre-applied)
    const int bn_sub = lane >> 3;     // 0..7 row within 8-row issue
    const int gcol   = ((lane & 7) ^ bn_sub) * 8;

    // ---- frag read pointers (k-step invariant)
    const ushort_t* ard[2][2];
    const ushort_t* brd[2][4];
#pragma unroll
    for (int ks = 0; ks < 2; ++ks) {
        const int ch = ((ks * 4 + lq) ^ (lm & 7)) * 8;
#pragma unroll
        for (int mi = 0; mi < 2; ++mi)
            ard[ks][mi] = &As[(wm + mi * 16 + lm) * 64 + ch];
#pragma unroll
        for (int ni = 0; ni < 4; ++ni)
            brd[ks][ni] = &Bs[(wn + ni * 16 + lm) * 64 + ch];
    }

    f32x4 acc[2][4] = {};

    for (int kb = 0; kb < K_PE; kb += 64) {
        // B DMA first (longest latency, zero regs)
#pragma unroll
        for (int t = 0; t < 4; ++t) {
            const int iss = wave * 4 + t;
            const ushort_t* g = Wbf + (size_t)(ntile + iss * 8 + bn_sub) * K_PE + kb + gcol;
            gl_lds16(g, &Bs[iss * 8 * 64]);
        }
        // A stage: 16 fp32 -> 16 bf16, swizzled chunk writes
        {
            const int kk0 = kb + qt * 16;
            const int c   = kk0 >> 8;
            const int di  = (kk0 >> 4) & 15;
            const float* ap = aptr + (c * 224 + di) * 224;
            float4 f0 = *(const float4*)(ap);
            float4 f1 = *(const float4*)(ap + 4);
            float4 f2 = *(const float4*)(ap + 8);
            float4 f3 = *(const float4*)(ap + 12);
            uint4 p0, p1;
            p0.x = bfpack(f0.x, f0.y); p0.y = bfpack(f0.z, f0.w);
            p0.z = bfpack(f1.x, f1.y); p0.w = bfpack(f1.z, f1.w);
            p1.x = bfpack(f2.x, f2.y); p1.y = bfpack(f2.z, f2.w);
            p1.z = bfpack(f3.x, f3.y); p1.w = bfpack(f3.z, f3.w);
            *(uint4*)aw0 = p0;
            *(uint4*)aw1 = p1;
        }
        __syncthreads();
#pragma unroll
        for (int ks = 0; ks < 2; ++ks) {
            short8 af[2], bfr[4];
#pragma unroll
            for (int mi = 0; mi < 2; ++mi) af[mi]  = *(const short8*)ard[ks][mi];
#pragma unroll
            for (int ni = 0; ni < 4; ++ni) bfr[ni] = *(const short8*)brd[ks][ni];
#pragma unroll
            for (int mi = 0; mi < 2; ++mi)
#pragma unroll
                for (int ni = 0; ni < 4; ++ni)
                    acc[mi][ni] = __builtin_amdgcn_mfma_f32_16x16x32_bf16(
                        af[mi], bfr[ni], acc[mi][ni], 0, 0, 0);
        }
        __syncthreads();
    }

    // Epilogue: D layout col=lane&15, row=(lane>>4)*4+reg. Bias + bf16 store.
#pragma unroll
    for (int ni = 0; ni < 4; ++ni) {
        const int col = ntile + wn + ni * 16 + lm;
        const float bv = bias[col];
#pragma unroll
        for (int mi = 0; mi < 2; ++mi) {
            const int row0 = mtile + wm + mi * 16 + lq * 4;
#pragma unroll
            for (int r = 0; r < 4; ++r)
                outp[(size_t)(row0 + r) * HID + col] = f2bf(acc[mi][ni][r] + bv);
        }
    }
}

// ---------------- row softmax / log-softmax, bf16, vectorized ---------------
// grid (3136, 2): 4 rows/block, 1 wave/row, lanes 0..47 hold 8 elems each.
__global__ __launch_bounds__(256) void softmax_bf16(ushort_t* __restrict__ xe,
                                                    ushort_t* __restrict__ ye) {
    const int rowi = blockIdx.x * 4 + (threadIdx.x >> 6);
    const int lane = threadIdx.x & 63;
    ushort_t* row = (blockIdx.y ? ye : xe) + (size_t)rowi * HID;
    const bool act = lane < 48;
    float v[8];
    float m = -3.4e38f;
    if (act) {
        uint4 pk = *(const uint4*)(row + lane * 8);
        v[0] = bflo(pk.x); v[1] = bfhi(pk.x);
        v[2] = bflo(pk.y); v[3] = bfhi(pk.y);
        v[4] = bflo(pk.z); v[5] = bfhi(pk.z);
        v[6] = bflo(pk.w); v[7] = bfhi(pk.w);
#pragma unroll
        for (int p = 0; p < 8; ++p) m = fmaxf(m, v[p]);
    }
#pragma unroll
    for (int off = 32; off > 0; off >>= 1) m = fmaxf(m, __shfl_xor(m, off));
    float s = 0.f;
    if (act) {
#pragma unroll
        for (int p = 0; p < 8; ++p) { v[p] -= m; s += __expf(v[p]); }
    }
#pragma unroll
    for (int off = 32; off > 0; off >>= 1) s += __shfl_xor(s, off);
    if (act) {
        uint4 pk;
        if (blockIdx.y == 0) {
            float ls = __logf(s);
#pragma unroll
            for (int p = 0; p < 8; ++p) v[p] -= ls;
        } else {
            float inv = 1.f / s;
#pragma unroll
            for (int p = 0; p < 8; ++p) v[p] = __expf(v[p]) * inv;
        }
        pk.x = bfpack(v[0], v[1]); pk.y = bfpack(v[2], v[3]);
        pk.z = bfpack(v[4], v[5]); pk.w = bfpack(v[6], v[7]);
        *(uint4*)(row + lane * 8) = pk;
    }
}

// ---------------- CE reduce: rank-1 restructure -----------------------------
// T = sum_i dot(logp_i, q_i)            (trace of the raw dot matrix)
// S = sum_col (sum_i logp[i,col]) * (sum_j q[j,col])   (total sum, rank-1)
// Each thread owns 8 contiguous cols of the 75264-wide layout, loops 64 rows.
__global__ __launch_bounds__(256) void reduce_ce(const ushort_t* __restrict__ logp,
                                                 const ushort_t* __restrict__ q,
                                                 float* __restrict__ scal) {
    const int gid = blockIdx.x * 256 + threadIdx.x;
    const int col = gid * 8;
    float T = 0.f, S = 0.f;
    if (col < K_CE) {
        float Ls[8] = {}, Qs[8] = {};
        for (int i = 0; i < 64; ++i) {
            uint4 lp = *(const uint4*)(logp + (size_t)i * K_CE + col);
            uint4 qp = *(const uint4*)(q    + (size_t)i * K_CE + col);
            float l[8], qq[8];
            l[0] = bflo(lp.x); l[1] = bfhi(lp.x); l[2] = bflo(lp.y); l[3] = bfhi(lp.y);
            l[4] = bflo(lp.z); l[5] = bfhi(lp.z); l[6] = bflo(lp.w); l[7] = bfhi(lp.w);
            qq[0] = bflo(qp.x); qq[1] = bfhi(qp.x); qq[2] = bflo(qp.y); qq[3] = bfhi(qp.y);
            qq[4] = bflo(qp.z); qq[5] = bfhi(qp.z); qq[6] = bflo(qp.w); qq[7] = bfhi(qp.w);
#pragma unroll
            for (int j = 0; j < 8; ++j) {
                T += l[j] * qq[j];
                Ls[j] += l[j];
                Qs[j] += qq[j];
            }
        }
#pragma unroll
        for (int j = 0; j < 8; ++j) S += Ls[j] * Qs[j];
    }
    // block reduction
#pragma unroll
    for (int off = 32; off > 0; off >>= 1) {
        T += __shfl_xor(T, off);
        S += __shfl_xor(S, off);
    }
    __shared__ float sT[4], sS[4];
    const int wave = threadIdx.x >> 6;
    if ((threadIdx.x & 63) == 0) { sT[wave] = T; sS[wave] = S; }
    __syncthreads();
    if (threadIdx.x == 0) {
        atomicAdd(&scal[0], sT[0] + sT[1] + sT[2] + sT[3]);
        atomicAdd(&scal[1], sS[0] + sS[1] + sS[2] + sS[3]);
    }
}

// ---------------- final scalar ----------------------------------------------
// close/far = (T/64) / ((S-T)/4032) = 63*T/(S-T); sign/scale factors cancel.
__global__ void final_k(const float* __restrict__ scal, float* __restrict__ out) {
    if (threadIdx.x == 0) {
        float T = scal[0], S = scal[1];
        out[0] = 63.f * T / (S - T);
    }
}

extern "C" void kernel_launch(void* const* d_in, const int* in_sizes, int n_in,
                              void* d_out, int out_size, void* d_ws, size_t ws_size,
                              hipStream_t stream) {
    const float* x = (const float*)d_in[0];   // (64,3,224,224)
    const float* y = (const float*)d_in[1];   // (64,3,224,224)
    const float* W = (const float*)d_in[2];   // (384,768)
    const float* b = (const float*)d_in[3];   // (384,)
    float* out = (float*)d_out;

    float*    scal = (float*)d_ws;                       // 4 f32 (T, S)
    ushort_t* Wbf  = (ushort_t*)((char*)d_ws + 64);      // 294912 bf16
    ushort_t* xe   = Wbf + 294912;                       // 12544*384 bf16
    ushort_t* ye   = xe + (size_t)M_TOT * HID;           // 12544*384 bf16

    prep<<<144, 256, 0, stream>>>(W, Wbf, scal);
    patch_embed_mfma<<<dim3(196, 3, 2), 256, 0, stream>>>(x, y, Wbf, b, xe, ye);
    softmax_bf16<<<dim3(3136, 2), 256, 0, stream>>>(xe, ye);
    reduce_ce<<<37, 256, 0, stream>>>(xe, ye, scal);
    final_k<<<1, 64, 0, stream>>>(scal, out);
}

// Round 4
// 173.794 us; speedup vs baseline: 2.3123x; 1.0469x over previous
//
#include <hip/hip_runtime.h>

#define M_TOT 12544   // 64 images * 196 patches
#define HID   384
#define K_PE  768     // 3*16*16
#define K_CE  75264   // 196*384 per image

typedef unsigned short ushort_t;
using f32x4  = __attribute__((ext_vector_type(4))) float;
using short8 = __attribute__((ext_vector_type(8))) short;

// ---- bf16 helpers (RNE) ----------------------------------------------------
__device__ __forceinline__ unsigned short f2bf(float x) {
    union { float f; unsigned u; } v; v.f = x;
    return (unsigned short)((v.u + 0x7fffu + ((v.u >> 16) & 1u)) >> 16);
}
__device__ __forceinline__ unsigned bfpack(float lo, float hi) {
    union { float f; unsigned u; } a, b; a.f = lo; b.f = hi;
    unsigned ra = (a.u + 0x7fffu + ((a.u >> 16) & 1u)) >> 16;
    unsigned rb = (b.u + 0x7fffu + ((b.u >> 16) & 1u)) & 0xffff0000u;
    return ra | rb;
}
__device__ __forceinline__ float bflo(unsigned u) {
    union { unsigned u; float f; } v; v.u = u << 16; return v.f;
}
__device__ __forceinline__ float bfhi(unsigned u) {
    union { unsigned u; float f; } v; v.u = u & 0xffff0000u; return v.f;
}

// ---- async global->LDS, 16 B per lane (LDS dest = wave-uniform base) -------
__device__ __forceinline__ void gl_lds16(const void* g, void* l) {
    __builtin_amdgcn_global_load_lds(
        (const __attribute__((address_space(1))) unsigned*)g,
        (__attribute__((address_space(3))) unsigned*)l, 16, 0, 0);
}

// ---------------- prep: zero scalars + convert W to bf16 --------------------
__global__ __launch_bounds__(256) void prep(const float* __restrict__ W,
                                            ushort_t* __restrict__ Wbf,
                                            float* __restrict__ scal) {
    int idx = blockIdx.x * 256 + threadIdx.x;
    if (idx < 4) scal[idx] = 0.f;
    const float4 a = *(const float4*)(W + (size_t)idx * 8);
    const float4 b = *(const float4*)(W + (size_t)idx * 8 + 4);
    uint4 p;
    p.x = bfpack(a.x, a.y); p.y = bfpack(a.z, a.w);
    p.z = bfpack(b.x, b.y); p.w = bfpack(b.z, b.w);
    ((uint4*)Wbf)[idx] = p;
}

// ---------------- fused patch-embed GEMM + softmax --------------------------
// M-tile 64, full N=384, K=768 streamed in 64-chunks. grid (196, 2) [y = x|e].
// Block 256 = 4 waves; wave tile 64M x 96N (4x6 frags of 16x16x32).
// A read ONCE from global (fp32->bf16 fused); B (W bf16) staged per K-step
// via global_load_lds from L2. Epilogue: row softmax on fp32 accumulators
// (16-lane butterfly + LDS cross-wave combine), store logp / q as bf16.
__global__ __launch_bounds__(256) void pe_softmax(
    const float* __restrict__ xin, const float* __restrict__ yin,
    const ushort_t* __restrict__ Wbf, const float* __restrict__ bias,
    ushort_t* __restrict__ xe, ushort_t* __restrict__ ye) {
    const float* im   = blockIdx.y ? yin : xin;
    ushort_t*    outp = blockIdx.y ? ye  : xe;
    const int mtile = blockIdx.x * 64;

    __shared__ __align__(16) ushort_t As[64 * 64];    //  8 KB
    __shared__ __align__(16) ushort_t Bs[384 * 64];   // 48 KB
    __shared__ float Sm[4][64];                       //  1 KB
    __shared__ float Ss[4][64];                       //  1 KB

    const int tid  = threadIdx.x;
    const int wave = tid >> 6;
    const int lane = tid & 63;
    const int lm   = lane & 15;
    const int lq   = lane >> 4;
    const int wn   = wave * 96;

    // ---- A staging ids: thread -> (row sm, 16-elem k-seg qt)
    const int sm = tid >> 2;          // 0..63
    const int qt = tid & 3;           // 0..3
    int mg = mtile + sm;
    int pb = mg / 196;
    int pr = mg - pb * 196;
    int pi = pr / 14;
    int pj = pr - pi * 14;
    const float* aptr = im + ((size_t)(pb * 3) * 224 + pi * 16) * 224 + pj * 16;
    ushort_t* aw0 = &As[sm * 64 + (((qt * 2    ) ^ (sm & 7)) * 8)];
    ushort_t* aw1 = &As[sm * 64 + (((qt * 2 + 1) ^ (sm & 7)) * 8)];

    // ---- B staging: lane-fixed global column offset (XOR pre-applied)
    const int bn_sub = lane >> 3;     // 0..7
    const int gcol   = ((lane & 7) ^ bn_sub) * 8;

    // ---- frag read pointers (k-step invariant)
    const ushort_t* ard[2][4];
    const ushort_t* brd[2][6];
#pragma unroll
    for (int ks = 0; ks < 2; ++ks) {
        const int ch = ((ks * 4 + lq) ^ (lm & 7)) * 8;
#pragma unroll
        for (int mi = 0; mi < 4; ++mi)
            ard[ks][mi] = &As[(mi * 16 + lm) * 64 + ch];
#pragma unroll
        for (int ni = 0; ni < 6; ++ni)
            brd[ks][ni] = &Bs[(wn + ni * 16 + lm) * 64 + ch];
    }

    f32x4 acc[4][6] = {};

    for (int kb = 0; kb < K_PE; kb += 64) {
        // B DMA first: 12 issues/wave covering all 384 rows x 64 k
#pragma unroll
        for (int t = 0; t < 12; ++t) {
            const int iss = wave * 12 + t;
            const ushort_t* g = Wbf + (size_t)(iss * 8 + bn_sub) * K_PE + kb + gcol;
            gl_lds16(g, &Bs[iss * 8 * 64]);
        }
        // A stage: 16 fp32 -> 16 bf16, swizzled chunk writes
        {
            const int kk0 = kb + qt * 16;
            const int c   = kk0 >> 8;
            const int di  = (kk0 >> 4) & 15;
            const float* ap = aptr + (c * 224 + di) * 224;
            float4 f0 = *(const float4*)(ap);
            float4 f1 = *(const float4*)(ap + 4);
            float4 f2 = *(const float4*)(ap + 8);
            float4 f3 = *(const float4*)(ap + 12);
            uint4 p0, p1;
            p0.x = bfpack(f0.x, f0.y); p0.y = bfpack(f0.z, f0.w);
            p0.z = bfpack(f1.x, f1.y); p0.w = bfpack(f1.z, f1.w);
            p1.x = bfpack(f2.x, f2.y); p1.y = bfpack(f2.z, f2.w);
            p1.z = bfpack(f3.x, f3.y); p1.w = bfpack(f3.z, f3.w);
            *(uint4*)aw0 = p0;
            *(uint4*)aw1 = p1;
        }
        __syncthreads();
#pragma unroll
        for (int ks = 0; ks < 2; ++ks) {
            short8 af[4], bfr[6];
#pragma unroll
            for (int mi = 0; mi < 4; ++mi) af[mi]  = *(const short8*)ard[ks][mi];
#pragma unroll
            for (int ni = 0; ni < 6; ++ni) bfr[ni] = *(const short8*)brd[ks][ni];
#pragma unroll
            for (int mi = 0; mi < 4; ++mi)
#pragma unroll
                for (int ni = 0; ni < 6; ++ni)
                    acc[mi][ni] = __builtin_amdgcn_mfma_f32_16x16x32_bf16(
                        af[mi], bfr[ni], acc[mi][ni], 0, 0, 0);
        }
        __syncthreads();
    }

    // ---- epilogue: bias + row softmax + store -------------------------------
    // D frag layout: col = wn + ni*16 + (lane&15), row = mi*16 + lq*4 + reg.
#pragma unroll
    for (int ni = 0; ni < 6; ++ni) {
        const float bv = bias[wn + ni * 16 + lm];
#pragma unroll
        for (int mi = 0; mi < 4; ++mi)
#pragma unroll
            for (int r = 0; r < 4; ++r)
                acc[mi][ni][r] += bv;
    }

    // pass 1: row max (over this wave's 96 cols), butterfly over the 16-lane group
    float mrow[4][4];
#pragma unroll
    for (int mi = 0; mi < 4; ++mi)
#pragma unroll
        for (int r = 0; r < 4; ++r) {
            float m = acc[mi][0][r];
#pragma unroll
            for (int ni = 1; ni < 6; ++ni) m = fmaxf(m, acc[mi][ni][r]);
            mrow[mi][r] = m;
        }
#pragma unroll
    for (int off = 1; off < 16; off <<= 1)
#pragma unroll
        for (int mi = 0; mi < 4; ++mi)
#pragma unroll
            for (int r = 0; r < 4; ++r)
                mrow[mi][r] = fmaxf(mrow[mi][r], __shfl_xor(mrow[mi][r], off));
    if (lm == 0)
#pragma unroll
        for (int mi = 0; mi < 4; ++mi)
#pragma unroll
            for (int r = 0; r < 4; ++r)
                Sm[wave][mi * 16 + lq * 4 + r] = mrow[mi][r];
    __syncthreads();
#pragma unroll
    for (int mi = 0; mi < 4; ++mi)
#pragma unroll
        for (int r = 0; r < 4; ++r) {
            const int row = mi * 16 + lq * 4 + r;
            float m = fmaxf(fmaxf(Sm[0][row], Sm[1][row]), fmaxf(Sm[2][row], Sm[3][row]));
            mrow[mi][r] = m;
        }

    // pass 2: row sum of exp
    float srow[4][4];
#pragma unroll
    for (int mi = 0; mi < 4; ++mi)
#pragma unroll
        for (int r = 0; r < 4; ++r) {
            float s = 0.f;
#pragma unroll
            for (int ni = 0; ni < 6; ++ni) s += __expf(acc[mi][ni][r] - mrow[mi][r]);
            srow[mi][r] = s;
        }
#pragma unroll
    for (int off = 1; off < 16; off <<= 1)
#pragma unroll
        for (int mi = 0; mi < 4; ++mi)
#pragma unroll
            for (int r = 0; r < 4; ++r)
                srow[mi][r] += __shfl_xor(srow[mi][r], off);
    if (lm == 0)
#pragma unroll
        for (int mi = 0; mi < 4; ++mi)
#pragma unroll
            for (int r = 0; r < 4; ++r)
                Ss[wave][mi * 16 + lq * 4 + r] = srow[mi][r];
    __syncthreads();
#pragma unroll
    for (int mi = 0; mi < 4; ++mi)
#pragma unroll
        for (int r = 0; r < 4; ++r) {
            const int row = mi * 16 + lq * 4 + r;
            srow[mi][r] = Ss[0][row] + Ss[1][row] + Ss[2][row] + Ss[3][row];
        }

    // pass 3: store logp (x) or q (y) as bf16
    if (blockIdx.y == 0) {
#pragma unroll
        for (int mi = 0; mi < 4; ++mi)
#pragma unroll
            for (int r = 0; r < 4; ++r) {
                const float sh = mrow[mi][r] + __logf(srow[mi][r]);
                const size_t grow = mtile + mi * 16 + lq * 4 + r;
#pragma unroll
                for (int ni = 0; ni < 6; ++ni)
                    outp[grow * HID + wn + ni * 16 + lm] = f2bf(acc[mi][ni][r] - sh);
            }
    } else {
#pragma unroll
        for (int mi = 0; mi < 4; ++mi)
#pragma unroll
            for (int r = 0; r < 4; ++r) {
                const float m   = mrow[mi][r];
                const float inv = 1.f / srow[mi][r];
                const size_t grow = mtile + mi * 16 + lq * 4 + r;
#pragma unroll
                for (int ni = 0; ni < 6; ++ni)
                    outp[grow * HID + wn + ni * 16 + lm] =
                        f2bf(__expf(acc[mi][ni][r] - m) * inv);
            }
    }
}

// ---------------- T/S reduce: one block per patch position ------------------
// T = sum_{i,p} dot(logp[i,p,:], q[i,p,:])
// S = sum_{p,c} (sum_i logp[i,p,c]) * (sum_j q[j,p,c])
// Block: 4 waves x 16 images each; lanes 0..47 hold 8 channels.
__global__ __launch_bounds__(256) void ts_reduce(const ushort_t* __restrict__ logp,
                                                 const ushort_t* __restrict__ q,
                                                 float* __restrict__ scal) {
    const int p    = blockIdx.x;          // 0..195
    const int wave = threadIdx.x >> 6;
    const int lane = threadIdx.x & 63;
    const bool act = lane < 48;
    float Ls[8] = {}, Qs[8] = {}, T = 0.f;
    for (int ii = 0; ii < 16; ++ii) {
        const int i = wave * 16 + ii;
        const size_t base = ((size_t)(i * 196 + p)) * HID + lane * 8;
        if (act) {
            uint4 lp = *(const uint4*)(logp + base);
            uint4 qp = *(const uint4*)(q + base);
            float l[8], qq[8];
            l[0] = bflo(lp.x); l[1] = bfhi(lp.x); l[2] = bflo(lp.y); l[3] = bfhi(lp.y);
            l[4] = bflo(lp.z); l[5] = bfhi(lp.z); l[6] = bflo(lp.w); l[7] = bfhi(lp.w);
            qq[0] = bflo(qp.x); qq[1] = bfhi(qp.x); qq[2] = bflo(qp.y); qq[3] = bfhi(qp.y);
            qq[4] = bflo(qp.z); qq[5] = bfhi(qp.z); qq[6] = bflo(qp.w); qq[7] = bfhi(qp.w);
#pragma unroll
            for (int j = 0; j < 8; ++j) {
                T += l[j] * qq[j];
                Ls[j] += l[j];
                Qs[j] += qq[j];
            }
        }
    }
#pragma unroll
    for (int off = 32; off > 0; off >>= 1) T += __shfl_xor(T, off);

    __shared__ float colL[4][384], colQ[4][384], sT[4];
    if (act)
#pragma unroll
        for (int j = 0; j < 8; ++j) {
            colL[wave][lane * 8 + j] = Ls[j];
            colQ[wave][lane * 8 + j] = Qs[j];
        }
    if (lane == 0) sT[wave] = T;
    __syncthreads();
    if (wave == 0) {
        float S = 0.f;
        if (act)
#pragma unroll
            for (int j = 0; j < 8; ++j) {
                const int c = lane * 8 + j;
                const float L = colL[0][c] + colL[1][c] + colL[2][c] + colL[3][c];
                const float Q = colQ[0][c] + colQ[1][c] + colQ[2][c] + colQ[3][c];
                S += L * Q;
            }
#pragma unroll
        for (int off = 32; off > 0; off >>= 1) S += __shfl_xor(S, off);
        if (lane == 0) {
            atomicAdd(&scal[0], sT[0] + sT[1] + sT[2] + sT[3]);
            atomicAdd(&scal[1], S);
        }
    }
}

// ---------------- final scalar ----------------------------------------------
// close/far = (T/64) / ((S-T)/4032) = 63*T/(S-T); -1/196 factors cancel.
__global__ void final_k(const float* __restrict__ scal, float* __restrict__ out) {
    if (threadIdx.x == 0) {
        float T = scal[0], S = scal[1];
        out[0] = 63.f * T / (S - T);
    }
}

extern "C" void kernel_launch(void* const* d_in, const int* in_sizes, int n_in,
                              void* d_out, int out_size, void* d_ws, size_t ws_size,
                              hipStream_t stream) {
    const float* x = (const float*)d_in[0];   // (64,3,224,224)
    const float* y = (const float*)d_in[1];   // (64,3,224,224)
    const float* W = (const float*)d_in[2];   // (384,768)
    const float* b = (const float*)d_in[3];   // (384,)
    float* out = (float*)d_out;

    float*    scal = (float*)d_ws;                       // 4 f32 (T, S)
    ushort_t* Wbf  = (ushort_t*)((char*)d_ws + 64);      // 294912 bf16
    ushort_t* xe   = Wbf + 294912;                       // 12544*384 bf16 (logp)
    ushort_t* ye   = xe + (size_t)M_TOT * HID;           // 12544*384 bf16 (q)

    prep<<<144, 256, 0, stream>>>(W, Wbf, scal);
    pe_softmax<<<dim3(196, 2), 256, 0, stream>>>(x, y, Wbf, b, xe, ye);
    ts_reduce<<<196, 256, 0, stream>>>(xe, ye, scal);
    final_k<<<1, 64, 0, stream>>>(scal, out);
}